// Round 6
// baseline (286.792 us; speedup 1.0000x reference)
//
#include <hip/hip_runtime.h>
#include <hip/hip_bf16.h>
#include <math.h>

// Problem constants
#define BATCH 64
#define SEQ   512
#define DIM   768
#define NW    256              // MAX_WORDS
#define NT    (BATCH * NW)     // 16384 tokens
#define KDIM  1536             // 2*DIM
#define HID   256              // router hidden
#define NL    7                // num labels

// GEMM tiling (R6: BM 32->64, grid 512->256, TPB 256->512)
#define BM  64
#define BK  64
#define BKP 72                 // padded LDS row stride (bf16) -> 144 B
#define NKT (KDIM / BK)        // 24

typedef __bf16 bf16_t;
typedef bf16_t bf16x4 __attribute__((ext_vector_type(4)));
typedef bf16_t bf16x8 __attribute__((ext_vector_type(8)));
typedef float  f32x4  __attribute__((ext_vector_type(4)));

// ---------------------------------------------------------------------------
// Kernel 1 (prep): convert router_w1 -> bf16 K-major tiles AND build the
// starts table. blocks 0..191 = w1 convert; blocks 192..319 = starts.
// ---------------------------------------------------------------------------
__global__ __launch_bounds__(256) void prep_kernel(
    const float* __restrict__ w1, bf16_t* __restrict__ w1t,
    const int* __restrict__ idh, const int* __restrict__ idr,
    int* __restrict__ starts)
{
    if (blockIdx.x < 192) {
        int kc = blockIdx.x >> 3;        // 0..23
        int kg = blockIdx.x & 7;         // 0..7
        int n  = threadIdx.x;            // 0..255
        bf16x8 v;
        #pragma unroll
        for (int j = 0; j < 8; j++)
            v[j] = (bf16_t)w1[(size_t)(kc * 64 + kg * 8 + j) * HID + n];
        *(bf16x8*)(w1t + (size_t)kc * (HID * BK) + n * BK + kg * 8) = v;
    } else {
        int blk = blockIdx.x - 192;      // 0..127 = 2 tensors x 64 batches
        int t = blk >> 6;
        int b = blk & 63;
        const int* ids = (t ? idr : idh) + b * SEQ;
        int w = threadIdx.x;
        int lo = 0, hi = SEQ;
        while (lo < hi) {
            int m = (lo + hi) >> 1;
            if (ids[m] < w) lo = m + 1; else hi = m;
        }
        int* row = starts + blk * 257;
        row[w] = lo;
        if (w == 0) row[256] = SEQ;
    }
}

// ---------------------------------------------------------------------------
// Kernel 2: segment-mean align — full-row wave-task (VERIFIED plateau, 87 us).
// R5 post-mortem: 5 structurally different variants (ILP gather, reg stream,
// LDS-DMA, thread gather, contiguous full-row) all land 85-98 us -> this
// gather+scatter mix plateaus at ~2.9 TB/s logical on this chip.  Frozen.
// ---------------------------------------------------------------------------
__global__ __launch_bounds__(256) void align_kernel(
    const float* __restrict__ hh, const float* __restrict__ hr,
    const int* __restrict__ starts, bf16_t* __restrict__ X)
{
    int tid  = threadIdx.x;
    int lane = tid & 63;
    int wv   = tid >> 6;
    int task = blockIdx.x * 4 + wv;      // 0..32767  (wave-uniform)
    int w    = task & 255;
    int t    = (task >> 8) & 1;
    int b    = task >> 9;

    const int* st = starts + (t * 64 + b) * 257;
    int lo = __builtin_amdgcn_readfirstlane(st[w]);
    int hi = __builtin_amdgcn_readfirstlane(st[w + 1]);
    int n  = hi - lo;

    const f32x4* src = (const f32x4*)((t ? hr : hh) + (size_t)b * SEQ * DIM) + lane;
    bf16_t*      xr  = X + (size_t)b * NW * KDIM + (size_t)w * KDIM + t * DIM;

    f32x4 a0 = {0.f,0.f,0.f,0.f}, a1 = a0, a2 = a0;
    for (int s = lo; s < hi; s++) {
        const f32x4* r = src + (size_t)s * 192;
        f32x4 v0 = r[0];
        f32x4 v1 = r[64];
        f32x4 v2 = r[128];
        a0 += v0; a1 += v1; a2 += v2;
    }
    float inv = n > 0 ? 1.0f / (float)n : 0.0f;
    bf16x4 o0, o1, o2;
    #pragma unroll
    for (int e = 0; e < 4; e++) {
        o0[e] = (bf16_t)(a0[e] * inv);
        o1[e] = (bf16_t)(a1[e] * inv);
        o2[e] = (bf16_t)(a2[e] * inv);
    }
    *(bf16x4*)(xr + lane * 4)         = o0;
    *(bf16x4*)(xr + (lane + 64) * 4)  = o1;
    *(bf16x4*)(xr + (lane + 128) * 4) = o2;
}

// ---------------------------------------------------------------------------
// Kernel 3 (FUSED): router GEMM -> alpha -> blend + head + l2.
//
// R6: BM 32->64, grid 512->256 (1 block/CU), TPB 512 (8 waves, 4M x 2N).
// Rationale: at BM=32 each of 512 blocks re-staged the full 36 KB w1t tile
// per kc step -> 442 MB of L2 reads (~1.7 MB/CU through LDS) + 24x2 staging
// latency exposures per CU.  BM=64 halves both; 8 waves/block keep SIMDs
// busy during staging.  Alpha/blend phases re-indexed for 64 tokens/block.
// ---------------------------------------------------------------------------
__global__ __launch_bounds__(512, 2) void gemm_blend_kernel(
    const bf16_t* __restrict__ X, const bf16_t* __restrict__ w1t,
    const float* __restrict__ b1, const float* __restrict__ w2,
    const float* __restrict__ b2, const float* __restrict__ hw,
    const float* __restrict__ hb, float* __restrict__ out)
{
    __shared__ __align__(16) unsigned char smem[BM * BKP * 2 + HID * BKP * 2];
    bf16_t (*Xs)[BKP] = (bf16_t (*)[BKP])smem;                   // 64 x 72
    bf16_t (*Ws)[BKP] = (bf16_t (*)[BKP])(smem + BM * BKP * 2);  // 256 x 72
    float*  hws       = (float*)(smem + BM * BKP * 2);           // reuses Ws
    __shared__ float alpha_acc[BM];
    __shared__ float alpha_s[BM];

    int tid   = threadIdx.x;             // 0..511
    int lane  = tid & 63;
    int wv    = tid >> 6;                // 0..7
    int mw    = wv >> 1;                 // 0..3  (16-token row tile)
    int nw    = wv & 1;                  // 0..1  (128-col half)
    int row16 = lane & 15;
    int quad  = lane >> 4;
    int tok0  = blockIdx.x * BM;

    f32x4 acc[8];                        // 16 tokens x 128 cols
    #pragma unroll
    for (int ni = 0; ni < 8; ni++)
        acc[ni] = (f32x4){0.f, 0.f, 0.f, 0.f};

    if (tid < BM) alpha_acc[tid] = 0.f;

    int xr = tid >> 3;                   // 0..63
    int xc = tid & 7;                    // 0..7

    for (int kc = 0; kc < NKT; kc++) {
        {   // Xs: 64 rows x 64 bf16 = 512 uint4, 1 per thread
            const uint4* src = (const uint4*)(X + (size_t)(tok0 + xr) * KDIM + kc * BK + xc * 8);
            *(uint4*)(&Xs[xr][xc * 8]) = *src;
        }
        {   // Ws: 256 rows x 64 bf16 = 2048 uint4, 4 per thread
            const uint4* srcb = (const uint4*)(w1t + (size_t)kc * (HID * BK));
            #pragma unroll
            for (int i = 0; i < 4; i++) {
                int cidx = tid + i * 512;
                *(uint4*)(&Ws[cidx >> 3][(cidx & 7) * 8]) = srcb[cidx];
            }
        }
        __syncthreads();
        #pragma unroll
        for (int kk2 = 0; kk2 < 2; kk2++) {
            bf16x8 af, bfg[8];
            af = *(const bf16x8*)(&Xs[mw * 16 + row16][kk2 * 32 + quad * 8]);
            #pragma unroll
            for (int ni = 0; ni < 8; ni++)
                bfg[ni] = *(const bf16x8*)(&Ws[nw * 128 + ni * 16 + row16][kk2 * 32 + quad * 8]);
            #pragma unroll
            for (int ni = 0; ni < 8; ni++)
                acc[ni] = __builtin_amdgcn_mfma_f32_16x16x32_bf16(
                    af, bfg[ni], acc[ni], 0, 0, 0);
        }
        __syncthreads();
    }

    // ---------------- alpha reduction ----------------
    {
        float w2v[8], b1v[8];
        #pragma unroll
        for (int ni = 0; ni < 8; ni++) {
            int col = nw * 128 + ni * 16 + row16;
            w2v[ni] = w2[col];
            b1v[ni] = b1[col];
        }
        #pragma unroll
        for (int r = 0; r < 4; r++) {
            float p = 0.f;
            #pragma unroll
            for (int ni = 0; ni < 8; ni++) {
                float v = acc[ni][r] + b1v[ni];
                v = v > 0.f ? v : 0.f;
                p += v * w2v[ni];
            }
            p += __shfl_xor(p, 1);
            p += __shfl_xor(p, 2);
            p += __shfl_xor(p, 4);
            p += __shfl_xor(p, 8);
            if (row16 == 0)
                atomicAdd(&alpha_acc[mw * 16 + quad * 4 + r], p);
        }
    }

    // stage head weights into the dead Ws region (Ws last read before the
    // final __syncthreads of the GEMM loop)
    for (int i = tid; i < DIM * NL; i += 512) {
        int d = i / NL, l = i - d * NL;
        hws[l * DIM + d] = hw[i];
    }
    __syncthreads();                      // alpha_acc final + hws staged

    if (tid < BM) {
        float a = 1.f / (1.f + expf(-(alpha_acc[tid] + b2[0])));
        alpha_s[tid] = a;
        out[(size_t)NT * NL + tok0 + tid] = a;
    }
    __syncthreads();                      // alpha_s visible

    // ---------------- blend + head + l2 (verified structure; 64 tok/block) --
    {
        int g   = lane >> 3;
        int u   = lane & 7;
        int tl  = wv * 8 + g;             // local token 0..63
        int tok = tok0 + tl;
        float a = alpha_s[tl];
        const bf16_t* xrow = X + (size_t)tok * KDIM;   // L2-hot (staged above)

        float lg[NL] = {0.f, 0.f, 0.f, 0.f, 0.f, 0.f, 0.f};
        float l2 = 0.f;

        #pragma unroll
        for (int k = 0; k < 12; k++) {
            int d0 = (k * 8 + u) * 8;
            bf16x8 hp = *(const bf16x8*)(xrow + d0);
            bf16x8 rp = *(const bf16x8*)(xrow + DIM + d0);
            float bl[8];
            #pragma unroll
            for (int e = 0; e < 8; e++) {
                float hhv = (float)hp[e];
                float hrv = (float)rp[e];
                float df  = hhv - hrv;
                bl[e] = fmaf(a, df, hrv);
                l2 = fmaf(df, df, l2);
            }
            #pragma unroll
            for (int l = 0; l < NL; l++) {
                f32x4 wA = *(const f32x4*)(&hws[l * DIM + d0]);
                f32x4 wB = *(const f32x4*)(&hws[l * DIM + d0 + 4]);
                lg[l] += bl[0]*wA[0] + bl[1]*wA[1] + bl[2]*wA[2] + bl[3]*wA[3]
                       + bl[4]*wB[0] + bl[5]*wB[1] + bl[6]*wB[2] + bl[7]*wB[3];
            }
        }

        #pragma unroll
        for (int off = 1; off < 8; off <<= 1) {
            #pragma unroll
            for (int l = 0; l < NL; l++) lg[l] += __shfl_xor(lg[l], off);
            l2 += __shfl_xor(l2, off);
        }

        if (u < NL) {
            float v = (u == 0) ? lg[0] : (u == 1) ? lg[1] : (u == 2) ? lg[2]
                    : (u == 3) ? lg[3] : (u == 4) ? lg[4] : (u == 5) ? lg[5] : lg[6];
            out[(size_t)tok * NL + u] = v + hb[u];
        } else {
            out[(size_t)NT * NL + NT + tok] = sqrtf(l2);
        }
    }
}

// ---------------------------------------------------------------------------
extern "C" void kernel_launch(void* const* d_in, const int* in_sizes, int n_in,
                              void* d_out, int out_size, void* d_ws, size_t ws_size,
                              hipStream_t stream)
{
    const float* hh  = (const float*)d_in[0];
    const float* hr  = (const float*)d_in[1];
    const int*   idh = (const int*)d_in[2];
    const int*   idr = (const int*)d_in[3];
    const float* w1  = (const float*)d_in[5];
    const float* b1  = (const float*)d_in[6];
    const float* w2  = (const float*)d_in[7];
    const float* b2  = (const float*)d_in[8];
    const float* hw  = (const float*)d_in[9];
    const float* hb  = (const float*)d_in[10];
    float* out = (float*)d_out;

    bf16_t* X      = (bf16_t*)d_ws;                        // 50.33 MB
    bf16_t* w1t    = X + (size_t)NT * KDIM;                // 0.79 MB (tiled)
    int*    starts = (int*)(w1t + (size_t)NKT * HID * BK); // 132 KB

    prep_kernel<<<320, 256, 0, stream>>>(w1, w1t, idh, idr, starts);
    align_kernel<<<8192, 256, 0, stream>>>(hh, hr, starts, X);
    gemm_blend_kernel<<<NT / BM, 512, 0, stream>>>(X, w1t, b1, w2, b2,
                                                   hw, hb, out);
}

// Round 7
// 280.978 us; speedup vs baseline: 1.0207x; 1.0207x over previous
//
#include <hip/hip_runtime.h>
#include <hip/hip_bf16.h>
#include <math.h>

// Problem constants
#define BATCH 64
#define SEQ   512
#define DIM   768
#define NW    256              // MAX_WORDS
#define NT    (BATCH * NW)     // 16384 tokens
#define KDIM  1536             // 2*DIM
#define HID   256              // router hidden
#define NL    7                // num labels

// GEMM tiling (measured-best R0/R3 config: BM=32, TPB=256, 3 blocks/CU)
#define BM  32
#define BK  64
#define BKP 72                 // padded LDS row stride (bf16) -> 144 B
#define NKT (KDIM / BK)        // 24

typedef __bf16 bf16_t;
typedef bf16_t bf16x4 __attribute__((ext_vector_type(4)));
typedef bf16_t bf16x8 __attribute__((ext_vector_type(8)));
typedef float  f32x4  __attribute__((ext_vector_type(4)));

// ---------------------------------------------------------------------------
// Kernel 1 (prep): convert router_w1 -> bf16 K-major tiles AND build the
// starts table. blocks 0..191 = w1 convert; blocks 192..319 = starts.
// ---------------------------------------------------------------------------
__global__ __launch_bounds__(256) void prep_kernel(
    const float* __restrict__ w1, bf16_t* __restrict__ w1t,
    const int* __restrict__ idh, const int* __restrict__ idr,
    int* __restrict__ starts)
{
    if (blockIdx.x < 192) {
        int kc = blockIdx.x >> 3;        // 0..23
        int kg = blockIdx.x & 7;         // 0..7
        int n  = threadIdx.x;            // 0..255
        bf16x8 v;
        #pragma unroll
        for (int j = 0; j < 8; j++)
            v[j] = (bf16_t)w1[(size_t)(kc * 64 + kg * 8 + j) * HID + n];
        *(bf16x8*)(w1t + (size_t)kc * (HID * BK) + n * BK + kg * 8) = v;
    } else {
        int blk = blockIdx.x - 192;      // 0..127 = 2 tensors x 64 batches
        int t = blk >> 6;
        int b = blk & 63;
        const int* ids = (t ? idr : idh) + b * SEQ;
        int w = threadIdx.x;
        int lo = 0, hi = SEQ;
        while (lo < hi) {
            int m = (lo + hi) >> 1;
            if (ids[m] < w) lo = m + 1; else hi = m;
        }
        int* row = starts + blk * 257;
        row[w] = lo;
        if (w == 0) row[256] = SEQ;
    }
}

// ---------------------------------------------------------------------------
// Kernel 2: segment-mean align — thread-level gather (R3 measured-best
// singles: 84.2-85.6 us) + XCD-aware block swizzle (T1).
//
// Plateau note (R0-R6): five structurally different variants (reg-ILP
// gather, reg streaming, LDS-DMA streaming, thread gather, contiguous
// full-row wave gather) all measure 85-98 us at ~1.5-1.8 TB/s HBM, 0 bank
// conflicts, 40-61% occupancy, VALUBusy 6-8%.  The plateau is insensitive
// to ILP shape, TLP count, DMA vs register, and read contiguity.  Frozen
// at the best-measured variant; the only untried lever with a matching
// mechanism is XCD L2 locality: adjacent blocks share boundary-row data
// and the per-(b,t) starts row, but round-robin dispatch scatters them
// across 8 private L2s.  nwg = 24576 = 8*3072 -> simple bijective swizzle.
// ---------------------------------------------------------------------------
__global__ __launch_bounds__(256) void align_kernel(
    const float* __restrict__ hh, const float* __restrict__ hr,
    const int* __restrict__ starts, bf16_t* __restrict__ X)
{
    // XCD swizzle: give each XCD a contiguous 3072-block range
    int bid  = blockIdx.x;
    int swz  = (bid & 7) * 3072 + (bid >> 3);

    int idx  = swz * 256 + threadIdx.x;            // 0 .. 6291455
    int rest = idx / 192;                          // (b,t,w) — wave-uniform
    int c    = idx - rest * 192;                   // f32x4 chunk within row
    rest     = __builtin_amdgcn_readfirstlane(rest);
    int w    = rest & 255;
    int t    = (rest >> 8) & 1;
    int b    = rest >> 9;

    const int* st = starts + (t * 64 + b) * 257;
    int lo = st[w];
    int hi = st[w + 1];

    const f32x4* src = (const f32x4*)((t ? hr : hh) + (size_t)b * SEQ * DIM);
    bf16_t*      dst = X + (size_t)b * NW * KDIM + (size_t)w * KDIM
                         + t * DIM + c * 4;

    bf16x4 o = {};
    int n = hi - lo;
    if (n > 0) {
        f32x4 acc = src[(size_t)lo * 192 + c];
        for (int s = lo + 1; s < hi; s++) {
            f32x4 v = src[(size_t)s * 192 + c];
            acc[0] += v[0]; acc[1] += v[1];
            acc[2] += v[2]; acc[3] += v[3];
        }
        float inv = 1.0f / (float)n;
        o[0] = (bf16_t)(acc[0] * inv);
        o[1] = (bf16_t)(acc[1] * inv);
        o[2] = (bf16_t)(acc[2] * inv);
        o[3] = (bf16_t)(acc[3] * inv);
    }
    *(bf16x4*)dst = o;
}

// ---------------------------------------------------------------------------
// Kernel 3: router GEMM (bf16 MFMA) via LDS -> alpha.  (R0/R3 verified-best)
// ---------------------------------------------------------------------------
__global__ __launch_bounds__(256) void gemm_alpha_kernel(
    const bf16_t* __restrict__ X, const bf16_t* __restrict__ w1t,
    const float* __restrict__ b1, const float* __restrict__ w2,
    const float* __restrict__ b2, float* __restrict__ out)
{
    __shared__ __align__(16) bf16_t Xs[BM][BKP];
    __shared__ __align__(16) bf16_t Ws[HID][BKP];
    __shared__ float alpha_acc[BM];

    int tid   = threadIdx.x;
    int lane  = tid & 63;
    int wv    = tid >> 6;
    int row16 = lane & 15;
    int quad  = lane >> 4;
    int tok0  = blockIdx.x * BM;

    f32x4 acc[2][4];
    #pragma unroll
    for (int mi = 0; mi < 2; mi++)
        #pragma unroll
        for (int ni = 0; ni < 4; ni++)
            acc[mi][ni] = (f32x4){0.f, 0.f, 0.f, 0.f};

    int xr = tid >> 3;
    int xc = tid & 7;

    for (int kc = 0; kc < NKT; kc++) {
        {
            const uint4* src = (const uint4*)(X + (size_t)(tok0 + xr) * KDIM + kc * BK + xc * 8);
            *(uint4*)(&Xs[xr][xc * 8]) = *src;
        }
        {
            const uint4* srcb = (const uint4*)(w1t + (size_t)kc * (HID * BK));
            #pragma unroll
            for (int i = 0; i < 8; i++) {
                int cidx = tid + i * 256;
                *(uint4*)(&Ws[cidx >> 3][(cidx & 7) * 8]) = srcb[cidx];
            }
        }
        __syncthreads();
        #pragma unroll
        for (int kk2 = 0; kk2 < 2; kk2++) {
            bf16x8 af[2], bfg[4];
            #pragma unroll
            for (int mi = 0; mi < 2; mi++)
                af[mi] = *(const bf16x8*)(&Xs[mi * 16 + row16][kk2 * 32 + quad * 8]);
            #pragma unroll
            for (int ni = 0; ni < 4; ni++)
                bfg[ni] = *(const bf16x8*)(&Ws[wv * 64 + ni * 16 + row16][kk2 * 32 + quad * 8]);
            #pragma unroll
            for (int mi = 0; mi < 2; mi++)
                #pragma unroll
                for (int ni = 0; ni < 4; ni++)
                    acc[mi][ni] = __builtin_amdgcn_mfma_f32_16x16x32_bf16(
                        af[mi], bfg[ni], acc[mi][ni], 0, 0, 0);
        }
        __syncthreads();
    }

    float w2v[4], b1v[4];
    #pragma unroll
    for (int ni = 0; ni < 4; ni++) {
        int col = wv * 64 + ni * 16 + row16;
        w2v[ni] = w2[col];
        b1v[ni] = b1[col];
    }
    if (tid < BM) alpha_acc[tid] = 0.f;
    __syncthreads();

    #pragma unroll
    for (int mi = 0; mi < 2; mi++) {
        #pragma unroll
        for (int r = 0; r < 4; r++) {
            float p = 0.f;
            #pragma unroll
            for (int ni = 0; ni < 4; ni++) {
                float v = acc[mi][ni][r] + b1v[ni];
                v = v > 0.f ? v : 0.f;
                p += v * w2v[ni];
            }
            p += __shfl_xor(p, 1);
            p += __shfl_xor(p, 2);
            p += __shfl_xor(p, 4);
            p += __shfl_xor(p, 8);
            if (row16 == 0)
                atomicAdd(&alpha_acc[mi * 16 + quad * 4 + r], p);
        }
    }
    __syncthreads();
    if (tid < BM) {
        float a = 1.f / (1.f + expf(-(alpha_acc[tid] + b2[0])));
        out[(size_t)NT * NL + tok0 + tid] = a;
    }
}

// ---------------------------------------------------------------------------
// Kernel 4: blend + head + l2. 8 tokens per wave. Grid 512. (R0/R3 verified)
// ---------------------------------------------------------------------------
__global__ __launch_bounds__(256) void blend_kernel(
    const bf16_t* __restrict__ X, const float* __restrict__ hw,
    const float* __restrict__ hb, float* __restrict__ out)
{
    __shared__ float hws[NL * DIM];       // [l][d]
    int tid  = threadIdx.x;
    int lane = tid & 63;
    int wv   = tid >> 6;

    for (int i = tid; i < DIM * NL; i += 256) {
        int d = i / NL, l = i - d * NL;
        hws[l * DIM + d] = hw[i];
    }
    __syncthreads();

    int g   = lane >> 3;
    int u   = lane & 7;
    int tok = blockIdx.x * 32 + wv * 8 + g;

    float a = out[(size_t)NT * NL + tok];
    const bf16_t* xrow = X + (size_t)tok * KDIM;

    float lg[NL] = {0.f, 0.f, 0.f, 0.f, 0.f, 0.f, 0.f};
    float l2 = 0.f;

    #pragma unroll
    for (int k = 0; k < 12; k++) {
        int d0 = (k * 8 + u) * 8;
        bf16x8 hp = *(const bf16x8*)(xrow + d0);
        bf16x8 rp = *(const bf16x8*)(xrow + DIM + d0);
        float bl[8];
        #pragma unroll
        for (int e = 0; e < 8; e++) {
            float hhv = (float)hp[e];
            float hrv = (float)rp[e];
            float df  = hhv - hrv;
            bl[e] = fmaf(a, df, hrv);
            l2 = fmaf(df, df, l2);
        }
        #pragma unroll
        for (int l = 0; l < NL; l++) {
            f32x4 wA = *(const f32x4*)(&hws[l * DIM + d0]);
            f32x4 wB = *(const f32x4*)(&hws[l * DIM + d0 + 4]);
            lg[l] += bl[0]*wA[0] + bl[1]*wA[1] + bl[2]*wA[2] + bl[3]*wA[3]
                   + bl[4]*wB[0] + bl[5]*wB[1] + bl[6]*wB[2] + bl[7]*wB[3];
        }
    }

    #pragma unroll
    for (int off = 1; off < 8; off <<= 1) {
        #pragma unroll
        for (int l = 0; l < NL; l++) lg[l] += __shfl_xor(lg[l], off);
        l2 += __shfl_xor(l2, off);
    }

    if (u < NL) {
        float v = (u == 0) ? lg[0] : (u == 1) ? lg[1] : (u == 2) ? lg[2]
                : (u == 3) ? lg[3] : (u == 4) ? lg[4] : (u == 5) ? lg[5] : lg[6];
        out[(size_t)tok * NL + u] = v + hb[u];
    } else {
        out[(size_t)NT * NL + NT + tok] = sqrtf(l2);
    }
}

// ---------------------------------------------------------------------------
extern "C" void kernel_launch(void* const* d_in, const int* in_sizes, int n_in,
                              void* d_out, int out_size, void* d_ws, size_t ws_size,
                              hipStream_t stream)
{
    const float* hh  = (const float*)d_in[0];
    const float* hr  = (const float*)d_in[1];
    const int*   idh = (const int*)d_in[2];
    const int*   idr = (const int*)d_in[3];
    const float* w1  = (const float*)d_in[5];
    const float* b1  = (const float*)d_in[6];
    const float* w2  = (const float*)d_in[7];
    const float* b2  = (const float*)d_in[8];
    const float* hw  = (const float*)d_in[9];
    const float* hb  = (const float*)d_in[10];
    float* out = (float*)d_out;

    bf16_t* X      = (bf16_t*)d_ws;                        // 50.33 MB
    bf16_t* w1t    = X + (size_t)NT * KDIM;                // 0.79 MB (tiled)
    int*    starts = (int*)(w1t + (size_t)NKT * HID * BK); // 132 KB

    prep_kernel<<<320, 256, 0, stream>>>(w1, w1t, idh, idr, starts);
    align_kernel<<<24576, 256, 0, stream>>>(hh, hr, starts, X);
    gemm_alpha_kernel<<<NT / BM, 256, 0, stream>>>(X, w1t, b1, w2, b2, out);
    blend_kernel<<<512, 256, 0, stream>>>(X, hw, hb, out);
}

// Round 8
// 275.606 us; speedup vs baseline: 1.0406x; 1.0195x over previous
//
#include <hip/hip_runtime.h>
#include <hip/hip_bf16.h>
#include <math.h>

// Problem constants
#define BATCH 64
#define SEQ   512
#define DIM   768
#define NW    256              // MAX_WORDS
#define NT    (BATCH * NW)     // 16384 tokens
#define KDIM  1536             // 2*DIM
#define HID   256              // router hidden
#define NL    7                // num labels

// GEMM tiling (measured-best: BM=32, TPB=256, 3 blocks/CU)
#define BM  32
#define BK  64
#define BKP 72                 // padded LDS row stride (bf16) -> 144 B
#define NKT (KDIM / BK)        // 24

typedef __bf16 bf16_t;
typedef bf16_t bf16x4 __attribute__((ext_vector_type(4)));
typedef bf16_t bf16x8 __attribute__((ext_vector_type(8)));
typedef float  f32x4  __attribute__((ext_vector_type(4)));

// ---------------------------------------------------------------------------
// Kernel 1 (prep): convert router_w1 -> bf16 K-major tiles AND build the
// starts table. blocks 0..191 = w1 convert; blocks 192..319 = starts.
// ---------------------------------------------------------------------------
__global__ __launch_bounds__(256) void prep_kernel(
    const float* __restrict__ w1, bf16_t* __restrict__ w1t,
    const int* __restrict__ idh, const int* __restrict__ idr,
    int* __restrict__ starts)
{
    if (blockIdx.x < 192) {
        int kc = blockIdx.x >> 3;        // 0..23
        int kg = blockIdx.x & 7;         // 0..7
        int n  = threadIdx.x;            // 0..255
        bf16x8 v;
        #pragma unroll
        for (int j = 0; j < 8; j++)
            v[j] = (bf16_t)w1[(size_t)(kc * 64 + kg * 8 + j) * HID + n];
        *(bf16x8*)(w1t + (size_t)kc * (HID * BK) + n * BK + kg * 8) = v;
    } else {
        int blk = blockIdx.x - 192;      // 0..127 = 2 tensors x 64 batches
        int t = blk >> 6;
        int b = blk & 63;
        const int* ids = (t ? idr : idh) + b * SEQ;
        int w = threadIdx.x;
        int lo = 0, hi = SEQ;
        while (lo < hi) {
            int m = (lo + hi) >> 1;
            if (ids[m] < w) lo = m + 1; else hi = m;
        }
        int* row = starts + blk * 257;
        row[w] = lo;
        if (w == 0) row[256] = SEQ;
    }
}

// ---------------------------------------------------------------------------
// Kernel 2: segment-mean align — thread-level gather + XCD swizzle (R7,
// best measured: 81.7-83.9 us) + 2-wide ILP unroll on the n-loop.
//
// Plateau record (R0-R7): reg-ILP gather, reg streaming, LDS-DMA, thread
// gather, contiguous full-row, XCD swizzle -> 82-98 us, ~3 TB/s logical.
// The one untested micro-lever IN THIS variant: at VGPR=8 the n-loop is a
// dependent load->add chain (1 load in flight/thread).  Pairwise unroll
// with two independent accumulators doubles in-flight loads for the
// dominant n=2 case; straightline body resists allocator flattening.
// ---------------------------------------------------------------------------
__global__ __launch_bounds__(256) void align_kernel(
    const float* __restrict__ hh, const float* __restrict__ hr,
    const int* __restrict__ starts, bf16_t* __restrict__ X)
{
    // XCD swizzle: each XCD gets a contiguous 3072-block range (24576 = 8*3072)
    int bid  = blockIdx.x;
    int swz  = (bid & 7) * 3072 + (bid >> 3);

    int idx  = swz * 256 + threadIdx.x;            // 0 .. 6291455
    int rest = idx / 192;                          // (b,t,w) — wave-uniform
    int c    = idx - rest * 192;                   // f32x4 chunk within row
    rest     = __builtin_amdgcn_readfirstlane(rest);
    int w    = rest & 255;
    int t    = (rest >> 8) & 1;
    int b    = rest >> 9;

    const int* st = starts + (t * 64 + b) * 257;
    int lo = st[w];
    int hi = st[w + 1];

    const f32x4* src = (const f32x4*)((t ? hr : hh) + (size_t)b * SEQ * DIM);
    bf16_t*      dst = X + (size_t)b * NW * KDIM + (size_t)w * KDIM
                         + t * DIM + c * 4;

    bf16x4 o = {};
    int n = hi - lo;
    if (n > 0) {
        f32x4 acc0 = {0.f, 0.f, 0.f, 0.f};
        f32x4 acc1 = {0.f, 0.f, 0.f, 0.f};
        int s = lo;
        for (; s + 2 <= hi; s += 2) {
            f32x4 v0 = src[(size_t)s * 192 + c];        // independent pair:
            f32x4 v1 = src[(size_t)(s + 1) * 192 + c];  // 2 loads in flight
            acc0 += v0;
            acc1 += v1;
        }
        if (s < hi)
            acc0 += src[(size_t)s * 192 + c];
        acc0 += acc1;
        float inv = 1.0f / (float)n;
        o[0] = (bf16_t)(acc0[0] * inv);
        o[1] = (bf16_t)(acc0[1] * inv);
        o[2] = (bf16_t)(acc0[2] * inv);
        o[3] = (bf16_t)(acc0[3] * inv);
    }
    *(bf16x4*)dst = o;
}

// ---------------------------------------------------------------------------
// Kernel 3 (FUSED, R5-verified): router GEMM -> alpha -> blend + head + l2.
// Measured combined ~44.6 us vs ~47 split (R5 vs R7 ledger).  BM=32,
// 256 threads, 3 blocks/CU; hws reuses the dead Ws LDS region; blend
// re-reads this block's X slab from L2 (staged by the GEMM loop).
// ---------------------------------------------------------------------------
__global__ __launch_bounds__(256) void gemm_blend_kernel(
    const bf16_t* __restrict__ X, const bf16_t* __restrict__ w1t,
    const float* __restrict__ b1, const float* __restrict__ w2,
    const float* __restrict__ b2, const float* __restrict__ hw,
    const float* __restrict__ hb, float* __restrict__ out)
{
    __shared__ __align__(16) unsigned char smem[4608 + 36864];
    bf16_t (*Xs)[BKP] = (bf16_t (*)[BKP])smem;               // 32 x 72 bf16
    bf16_t (*Ws)[BKP] = (bf16_t (*)[BKP])(smem + 4608);      // 256 x 72 bf16
    float*  hws       = (float*)(smem + 4608);               // reuses Ws region
    __shared__ float alpha_acc[BM];
    __shared__ float alpha_s[BM];

    int tid   = threadIdx.x;
    int lane  = tid & 63;
    int wv    = tid >> 6;
    int row16 = lane & 15;
    int quad  = lane >> 4;
    int tok0  = blockIdx.x * BM;

    f32x4 acc[2][4];
    #pragma unroll
    for (int mi = 0; mi < 2; mi++)
        #pragma unroll
        for (int ni = 0; ni < 4; ni++)
            acc[mi][ni] = (f32x4){0.f, 0.f, 0.f, 0.f};

    int xr = tid >> 3;
    int xc = tid & 7;

    for (int kc = 0; kc < NKT; kc++) {
        {
            const uint4* src = (const uint4*)(X + (size_t)(tok0 + xr) * KDIM + kc * BK + xc * 8);
            *(uint4*)(&Xs[xr][xc * 8]) = *src;
        }
        {
            const uint4* srcb = (const uint4*)(w1t + (size_t)kc * (HID * BK));
            #pragma unroll
            for (int i = 0; i < 8; i++) {
                int cidx = tid + i * 256;
                *(uint4*)(&Ws[cidx >> 3][(cidx & 7) * 8]) = srcb[cidx];
            }
        }
        __syncthreads();
        #pragma unroll
        for (int kk2 = 0; kk2 < 2; kk2++) {
            bf16x8 af[2], bfg[4];
            #pragma unroll
            for (int mi = 0; mi < 2; mi++)
                af[mi] = *(const bf16x8*)(&Xs[mi * 16 + row16][kk2 * 32 + quad * 8]);
            #pragma unroll
            for (int ni = 0; ni < 4; ni++)
                bfg[ni] = *(const bf16x8*)(&Ws[wv * 64 + ni * 16 + row16][kk2 * 32 + quad * 8]);
            #pragma unroll
            for (int mi = 0; mi < 2; mi++)
                #pragma unroll
                for (int ni = 0; ni < 4; ni++)
                    acc[mi][ni] = __builtin_amdgcn_mfma_f32_16x16x32_bf16(
                        af[mi], bfg[ni], acc[mi][ni], 0, 0, 0);
        }
        __syncthreads();
    }

    // ---------------- alpha reduction ----------------
    float w2v[4], b1v[4];
    #pragma unroll
    for (int ni = 0; ni < 4; ni++) {
        int col = wv * 64 + ni * 16 + row16;
        w2v[ni] = w2[col];
        b1v[ni] = b1[col];
    }
    if (tid < BM) alpha_acc[tid] = 0.f;
    __syncthreads();

    #pragma unroll
    for (int mi = 0; mi < 2; mi++) {
        #pragma unroll
        for (int r = 0; r < 4; r++) {
            float p = 0.f;
            #pragma unroll
            for (int ni = 0; ni < 4; ni++) {
                float v = acc[mi][ni][r] + b1v[ni];
                v = v > 0.f ? v : 0.f;
                p += v * w2v[ni];
            }
            p += __shfl_xor(p, 1);
            p += __shfl_xor(p, 2);
            p += __shfl_xor(p, 4);
            p += __shfl_xor(p, 8);
            if (row16 == 0)
                atomicAdd(&alpha_acc[mi * 16 + quad * 4 + r], p);
        }
    }

    // stage head weights into the dead Ws region
    for (int i = tid; i < DIM * NL; i += 256) {
        int d = i / NL, l = i - d * NL;
        hws[l * DIM + d] = hw[i];
    }
    __syncthreads();                      // alpha_acc final + hws staged

    if (tid < BM) {
        float a = 1.f / (1.f + expf(-(alpha_acc[tid] + b2[0])));
        alpha_s[tid] = a;
        out[(size_t)NT * NL + tok0 + tid] = a;
    }
    __syncthreads();                      // alpha_s visible

    // ---------------- blend + head + l2 ----------------
    {
        int g   = lane >> 3;
        int u   = lane & 7;
        int tl  = wv * 8 + g;             // local token 0..31
        int tok = tok0 + tl;
        float a = alpha_s[tl];
        const bf16_t* xrow = X + (size_t)tok * KDIM;   // L2-hot (staged above)

        float lg[NL] = {0.f, 0.f, 0.f, 0.f, 0.f, 0.f, 0.f};
        float l2 = 0.f;

        #pragma unroll
        for (int k = 0; k < 12; k++) {
            int d0 = (k * 8 + u) * 8;
            bf16x8 hp = *(const bf16x8*)(xrow + d0);
            bf16x8 rp = *(const bf16x8*)(xrow + DIM + d0);
            float bl[8];
            #pragma unroll
            for (int e = 0; e < 8; e++) {
                float hhv = (float)hp[e];
                float hrv = (float)rp[e];
                float df  = hhv - hrv;
                bl[e] = fmaf(a, df, hrv);
                l2 = fmaf(df, df, l2);
            }
            #pragma unroll
            for (int l = 0; l < NL; l++) {
                f32x4 wA = *(const f32x4*)(&hws[l * DIM + d0]);
                f32x4 wB = *(const f32x4*)(&hws[l * DIM + d0 + 4]);
                lg[l] += bl[0]*wA[0] + bl[1]*wA[1] + bl[2]*wA[2] + bl[3]*wA[3]
                       + bl[4]*wB[0] + bl[5]*wB[1] + bl[6]*wB[2] + bl[7]*wB[3];
            }
        }

        #pragma unroll
        for (int off = 1; off < 8; off <<= 1) {
            #pragma unroll
            for (int l = 0; l < NL; l++) lg[l] += __shfl_xor(lg[l], off);
            l2 += __shfl_xor(l2, off);
        }

        if (u < NL) {
            float v = (u == 0) ? lg[0] : (u == 1) ? lg[1] : (u == 2) ? lg[2]
                    : (u == 3) ? lg[3] : (u == 4) ? lg[4] : (u == 5) ? lg[5] : lg[6];
            out[(size_t)tok * NL + u] = v + hb[u];
        } else {
            out[(size_t)NT * NL + NT + tok] = sqrtf(l2);
        }
    }
}

// ---------------------------------------------------------------------------
extern "C" void kernel_launch(void* const* d_in, const int* in_sizes, int n_in,
                              void* d_out, int out_size, void* d_ws, size_t ws_size,
                              hipStream_t stream)
{
    const float* hh  = (const float*)d_in[0];
    const float* hr  = (const float*)d_in[1];
    const int*   idh = (const int*)d_in[2];
    const int*   idr = (const int*)d_in[3];
    const float* w1  = (const float*)d_in[5];
    const float* b1  = (const float*)d_in[6];
    const float* w2  = (const float*)d_in[7];
    const float* b2  = (const float*)d_in[8];
    const float* hw  = (const float*)d_in[9];
    const float* hb  = (const float*)d_in[10];
    float* out = (float*)d_out;

    bf16_t* X      = (bf16_t*)d_ws;                        // 50.33 MB
    bf16_t* w1t    = X + (size_t)NT * KDIM;                // 0.79 MB (tiled)
    int*    starts = (int*)(w1t + (size_t)NKT * HID * BK); // 132 KB

    prep_kernel<<<320, 256, 0, stream>>>(w1, w1t, idh, idr, starts);
    align_kernel<<<24576, 256, 0, stream>>>(hh, hr, starts, X);
    gemm_blend_kernel<<<NT / BM, 256, 0, stream>>>(X, w1t, b1, w2, b2,
                                                   hw, hb, out);
}